// Round 7
// baseline (425.742 us; speedup 1.0000x reference)
//
#include <hip/hip_runtime.h>

#define LN_EPS 1e-5f

typedef __attribute__((ext_vector_type(8))) short bf16x8;
typedef __attribute__((ext_vector_type(4))) float f32x4;

__device__ __forceinline__ unsigned short f2bf(float f){
  unsigned u = __builtin_bit_cast(unsigned, f);
  u = (u + 0x7fffu + ((u >> 16) & 1u)) >> 16;
  return (unsigned short)u;
}
__device__ __forceinline__ float bf2f(unsigned short h){
  unsigned u = ((unsigned)h) << 16;
  return __builtin_bit_cast(float, u);
}
__device__ __forceinline__ unsigned pk2(float lo, float hi){
  return (unsigned)f2bf(lo) | ((unsigned)f2bf(hi) << 16);
}

// ---------------------------------------------------------------------------
// Kernel A (merged): z<24 -> cond LN + K/V projection; z==24 -> Wq prep.
// ---------------------------------------------------------------------------
__global__ void k_aux(const float* __restrict__ Wq, const float* __restrict__ ln_g,
                      const float* __restrict__ ln_b, const float* __restrict__ bq,
                      unsigned short* __restrict__ gWqT, float2* __restrict__ c12,
                      const float* __restrict__ cond, const int* __restrict__ idx,
                      const float* __restrict__ tg, const float* __restrict__ tb,
                      const float* __restrict__ Wk, const float* __restrict__ bk,
                      const float* __restrict__ Wv, const float* __restrict__ bv,
                      float* __restrict__ kbuf, float* __restrict__ vbuf)
{
  __shared__ float cn[16][768];
  const int tid = threadIdx.x;

  if(blockIdx.z == 24){
    // ---- prep role: 8 of the 20 (x,y) blocks ----
    const int pb = blockIdx.x + 4*blockIdx.y;
    if(pb >= 8) return;
    float* const r1 = &cn[0][0];          // [64][4]
    float* const r2 = &cn[0][0] + 256;    // [64][4]
    const int n0 = pb * 64;
    const int c = tid & 63, q = tid >> 6;
    const int n = n0 + c;
    float c1p = 0.f, c2p = 0.f;
    for(int i=0;i<128;i+=4){
      ushort4 pkv;
      unsigned short* pp = (unsigned short*)&pkv;
      #pragma unroll
      for(int j=0;j<4;j++){
        const int d = q*128 + i + j;
        const float wv = Wq[(size_t)d*512 + n];
        const unsigned short hb = f2bf(ln_g[d] * wv);
        pp[j] = hb;
        c2p += bf2f(hb);
        c1p += ln_b[d] * wv;
      }
      *(ushort4*)(gWqT + (size_t)n*512 + q*128 + i) = pkv;
    }
    r1[c*4 + q] = c1p; r2[c*4 + q] = c2p;
    __syncthreads();
    if(q == 0){
      float a = 0.f, b2 = 0.f;
      #pragma unroll
      for(int j=0;j<4;j++){ a += r1[c*4+j]; b2 += r2[c*4+j]; }
      c12[n] = make_float2(a + bq[n], b2);
    }
    return;
  }

  // ---- condkv role ----
  const int bc = blockIdx.z, nc = blockIdx.y, dc = blockIdx.x;
  const int b = idx[bc];
  const int n0 = nc * 16;
  int nrows = 77 - n0; if(nrows > 16) nrows = 16;
  const int w = tid >> 6, lane = tid & 63;

  for(int r = w; r < nrows; r += 4){
    const float* src = cond + ((size_t)b * 77 + n0 + r) * 768;
    float vals[12]; float s1 = 0.f, s2 = 0.f;
    #pragma unroll
    for(int i=0;i<12;i++){ float x = src[lane + i*64]; vals[i]=x; s1+=x; s2+=x*x; }
    #pragma unroll
    for(int off=1; off<64; off<<=1){ s1 += __shfl_xor(s1, off); s2 += __shfl_xor(s2, off); }
    const float mu  = s1 * (1.f/768.f);
    const float var = s2 * (1.f/768.f) - mu*mu;
    const float rs  = rsqrtf(var + LN_EPS);
    #pragma unroll
    for(int i=0;i<12;i++){ const int c2 = lane + i*64; cn[r][c2] = (vals[i]-mu)*rs*tg[c2] + tb[c2]; }
  }
  __syncthreads();

  const int dq = tid & 63;
  const int part = tid >> 6;
  const float* W    = (dc < 2) ? Wk : Wv;
  const float* bias = (dc < 2) ? bk : bv;
  float* obuf       = (dc < 2) ? kbuf : vbuf;
  const int d0 = (dc & 1) * 256 + dq * 4;

  float acc[4][4] = {};
  for(int i=0;i<768;i++){
    const float4 wv = *(const float4*)(W + (size_t)i * 512 + d0);
    #pragma unroll
    for(int j=0;j<4;j++){
      const float c = cn[part*4 + j][i];
      acc[j][0] += c * wv.x; acc[j][1] += c * wv.y;
      acc[j][2] += c * wv.z; acc[j][3] += c * wv.w;
    }
  }
  #pragma unroll
  for(int j=0;j<4;j++){
    const int r = part*4 + j, n = n0 + r;
    if(r < nrows){
      float4 o;
      o.x = acc[j][0] + bias[d0+0];
      o.y = acc[j][1] + bias[d0+1];
      o.z = acc[j][2] + bias[d0+2];
      o.w = acc[j][3] + bias[d0+3];
      *(float4*)(obuf + ((size_t)bc * 77 + n) * 512 + d0) = o;
    }
  }
}

// ---------------------------------------------------------------------------
// Kernel 2: softmax K over tokens; ctxP packed in MFMA-B-frag order
// ---------------------------------------------------------------------------
__global__ void k_ctx(const float* __restrict__ kbuf, const float* __restrict__ vbuf,
                      unsigned short* __restrict__ ctxP)
{
  __shared__ float kk[77][64];
  __shared__ float vv[77][64];
  __shared__ float inv_s[64];
  const int h = blockIdx.x, bc = blockIdx.y;
  const int tid = threadIdx.x;
  for(int e = tid; e < 77*64; e += 256){
    const int n = e >> 6, c = e & 63;
    kk[n][c] = kbuf[((size_t)bc * 77 + n) * 512 + h*64 + c];
    vv[n][c] = vbuf[((size_t)bc * 77 + n) * 512 + h*64 + c];
  }
  __syncthreads();
  if(tid < 64){
    float m = -1e30f;
    for(int n=0;n<77;n++) m = fmaxf(m, kk[n][tid]);
    float s = 0.f;
    for(int n=0;n<77;n++){ const float e = __expf(kk[n][tid] - m); kk[n][tid] = e; s += e; }
    inv_s[tid] = 1.f / s;
  }
  __syncthreads();
  #pragma unroll
  for(int j=0;j<16;j++){
    const int o = tid + 256*j;
    const int v = o >> 6, k2 = o & 63;
    float a = 0.f;
    for(int n=0;n<77;n++) a += kk[n][k2] * vv[n][v];
    const int pos = ((((k2>>5)*4 + (v>>4))*4 + ((k2>>3)&3))*16 + (v&15))*8 + (k2&7);
    ctxP[((size_t)(bc*8 + h)) * 4096 + pos] = f2bf(a * inv_s[k2]);
  }
}

// ---------------------------------------------------------------------------
// Kernel 3: fused GEMM+softmax+PV+residual, v3.
//  - BK=64, 8 K-steps; raw s_barrier (no vmcnt drain); loads issued at step top
//  - staging: thread owns row t, 16 d's -> two conflict-free b128 writes
//    (slot swizzle s ^ ((t>>1)&7), verified both sides)
//  - W-frags direct from L2 (gWqT), issued at step top
//  - LN folded at epilogue: q = rs*G - rs*mu*c2 + c1
// grid (2, 1792): by<1536 gemm (64t x 256n), else copy path.
// ---------------------------------------------------------------------------
__global__ __launch_bounds__(256, 3)
void k_fused(const float* __restrict__ input, const int* __restrict__ idx,
             const unsigned short* __restrict__ gWqT, const float2* __restrict__ c12,
             const unsigned short* __restrict__ ctxP, float* __restrict__ out)
{
  const int nt  = blockIdx.x;
  const int by  = blockIdx.y;
  const int tid = threadIdx.x;

  if(by >= 1536){
    const int cid = (by - 1536)*2 + nt;     // 0..511
    const int nb = cid >> 6, chunk = cid & 63;
    int cnt = 0, bsel = 0;
    for(int b2 = 0; b2 < 32; ++b2){
      bool member = false;
      #pragma unroll
      for(int i2 = 0; i2 < 24; ++i2) member |= (idx[i2] == b2);
      if(!member){ if(cnt == nb) bsel = b2; ++cnt; }
    }
    const float4* s = (const float4*)(input + (size_t)bsel * 2097152) + chunk*8192;
    float4*       d = (float4*)      (out   + (size_t)bsel * 2097152) + chunk*8192;
    #pragma unroll
    for(int i = 0; i < 32; ++i) d[i*256 + tid] = s[i*256 + tid];
    return;
  }

  __shared__ __align__(16) char smem[40960];
  // era1: X dbuf [2][64][128B] @0..16383
  // era2 (aliased): P @0 (36864B); mu @36864; rs @37120; red1 @37376; red2 @38400
  unsigned short* const P = (unsigned short*)smem;
  float* const mu_s = (float*)(smem + 36864);
  float* const rs_s = (float*)(smem + 37120);
  float* const red1 = (float*)(smem + 37376);
  float* const red2 = (float*)(smem + 38400);

  const int lane = tid & 63, w = tid >> 6;
  const int col = lane & 15, g = lane >> 4;
  const int bc = by >> 6, b = idx[bc];
  const int t0 = (by & 63) * 64;
  const int nbase = nt * 256;
  const float* xb = input + (size_t)b * 2097152;

  // staging: thread owns row t (t-local), d-slots q*16..q*16+15 per K-step
  const int t = tid & 63;
  const int q = tid >> 6;
  const float* xcol = xb + t0 + t;

  const int wxA = t*128 + ((((q<<1)    ) ^ ((t>>1)&7)) << 4);
  const int wxB = t*128 + ((((q<<1) | 1) ^ ((t>>1)&7)) << 4);

  int offA[2][4];
  #pragma unroll
  for(int kk=0; kk<2; ++kk)
    #pragma unroll
    for(int mt=0; mt<4; ++mt){
      const int row = mt*16 + col;
      offA[kk][mt] = row*128 + (((kk*4 + g) ^ ((row>>1)&7)) << 4);
    }

  const char* wrow[4];
  #pragma unroll
  for(int ntl=0; ntl<4; ++ntl)
    wrow[ntl] = (const char*)gWqT + (size_t)(nbase + w*64 + ntl*16 + col)*1024 + g*16;

  float s1 = 0.f, s2 = 0.f;
  f32x4 acc[4][4] = {};

  #define XLOAD(xv, ks)                                                       \
  { _Pragma("unroll")                                                         \
    for(int j=0;j<16;j++) xv[j] = xcol[(size_t)((ks)*64 + q*16 + j) * 4096]; }
  #define XSTAT(xv)                                                           \
  { _Pragma("unroll")                                                         \
    for(int j=0;j<16;j++){ s1 += xv[j]; s2 += xv[j]*xv[j]; } }
  #define XPUT(xv, Xd)                                                        \
  { uint4 ua, ub;                                                             \
    ua.x = pk2(xv[0],xv[1]);  ua.y = pk2(xv[2],xv[3]);                        \
    ua.z = pk2(xv[4],xv[5]);  ua.w = pk2(xv[6],xv[7]);                        \
    ub.x = pk2(xv[8],xv[9]);  ub.y = pk2(xv[10],xv[11]);                      \
    ub.z = pk2(xv[12],xv[13]);ub.w = pk2(xv[14],xv[15]);                      \
    *(uint4*)((Xd) + wxA) = ua;                                               \
    *(uint4*)((Xd) + wxB) = ub; }

  // prologue: stage step 0
  {
    float xv[16];
    XLOAD(xv, 0);
    XSTAT(xv);
    XPUT(xv, smem);
  }
  asm volatile("s_waitcnt lgkmcnt(0)" ::: "memory");
  __builtin_amdgcn_s_barrier();

  for(int ks = 0; ks < 8; ++ks){
    char* const Xc = smem + ((ks & 1) << 13);
    char* const Xn = smem + (((ks + 1) & 1) << 13);

    // issue next x tile + this step's W frags early (stay in flight; no drain)
    float xn[16];
    if(ks < 7){ XLOAD(xn, ks+1); }
    bf16x8 wf[2][4];
    #pragma unroll
    for(int kk=0; kk<2; ++kk)
      #pragma unroll
      for(int ntl=0; ntl<4; ++ntl)
        wf[kk][ntl] = *(const bf16x8*)(wrow[ntl] + ks*128 + kk*64);

    #pragma unroll
    for(int kk=0; kk<2; ++kk){
      bf16x8 af[4];
      #pragma unroll
      for(int mt=0; mt<4; ++mt) af[mt] = *(const bf16x8*)(Xc + offA[kk][mt]);
      #pragma unroll
      for(int ntl=0; ntl<4; ++ntl)
        #pragma unroll
        for(int mt=0; mt<4; ++mt)
          acc[mt][ntl] = __builtin_amdgcn_mfma_f32_16x16x32_bf16(af[mt], wf[kk][ntl], acc[mt][ntl], 0, 0, 0);
    }

    __builtin_amdgcn_s_barrier();   // reads of Xc complete block-wide

    if(ks < 7){
      XSTAT(xn);
      XPUT(xn, Xn);
      asm volatile("s_waitcnt lgkmcnt(0)" ::: "memory");
      __builtin_amdgcn_s_barrier(); // Xn visible block-wide
    }
  }
  #undef XLOAD
  #undef XSTAT
  #undef XPUT

  // ---- LN stats reduce: thread holds (t, q) partial ----
  red1[t*4 + q] = s1;
  red2[t*4 + q] = s2;
  __syncthreads();
  if(tid < 64){
    const float a  = red1[tid*4] + red1[tid*4+1] + red1[tid*4+2] + red1[tid*4+3];
    const float c2 = red2[tid*4] + red2[tid*4+1] + red2[tid*4+2] + red2[tid*4+3];
    const float mu  = a * (1.f/512.f);
    const float var = c2 * (1.f/512.f) - mu*mu;
    mu_s[tid] = mu;
    rs_s[tid] = rsqrtf(var + LN_EPS);
  }
  __syncthreads();

  // ---- LN fold + per-head feature softmax (wave owns one head) ----
  const int head = nt*4 + w;
  float c1b[4], c2v[4];
  #pragma unroll
  for(int ntl=0; ntl<4; ++ntl){
    const float2 cc = c12[nbase + w*64 + ntl*16 + col];
    c1b[ntl] = cc.x;   // includes bq
    c2v[ntl] = cc.y;
  }
  #pragma unroll
  for(int mt=0; mt<4; ++mt){
    #pragma unroll
    for(int r=0; r<4; ++r){
      const int tl = mt*16 + g*4 + r;
      const float rsr = rs_s[tl];
      const float mrc = rsr * mu_s[tl];
      float v[4];
      #pragma unroll
      for(int ntl=0; ntl<4; ++ntl)
        v[ntl] = rsr*acc[mt][ntl][r] - mrc*c2v[ntl] + c1b[ntl];
      float m = fmaxf(fmaxf(v[0],v[1]), fmaxf(v[2],v[3]));
      m = fmaxf(m, __shfl_xor(m, 1));
      m = fmaxf(m, __shfl_xor(m, 2));
      m = fmaxf(m, __shfl_xor(m, 4));
      m = fmaxf(m, __shfl_xor(m, 8));
      float s = 0.f;
      #pragma unroll
      for(int ntl=0; ntl<4; ++ntl){ v[ntl] = __expf(v[ntl] - m); s += v[ntl]; }
      s += __shfl_xor(s, 1);
      s += __shfl_xor(s, 2);
      s += __shfl_xor(s, 4);
      s += __shfl_xor(s, 8);
      const float inv = 1.f / s;
      #pragma unroll
      for(int ntl=0; ntl<4; ++ntl) acc[mt][ntl][r] = v[ntl] * inv;
    }
  }

  // ---- P -> LDS (wave-private), PV MFMA, residual + float4 store ----
  unsigned short* const Pw = P + w * (64*72);
  #pragma unroll
  for(int mt=0; mt<4; ++mt)
    #pragma unroll
    for(int ntl=0; ntl<4; ++ntl)
      #pragma unroll
      for(int r=0; r<4; ++r)
        Pw[(mt*16 + g*4 + r)*72 + ntl*16 + col] = f2bf(acc[mt][ntl][r]);

  const unsigned short* cp = ctxP + (size_t)(bc*8 + head) * 4096;
  f32x4 y[4][4] = {};
  #pragma unroll
  for(int ks2=0; ks2<2; ++ks2){
    bf16x8 pa[4];
    #pragma unroll
    for(int mt=0; mt<4; ++mt)
      pa[mt] = *(const bf16x8*)(Pw + (mt*16 + col)*72 + ks2*32 + g*8);
    bf16x8 cv[4];
    #pragma unroll
    for(int vt=0; vt<4; ++vt)
      cv[vt] = *(const bf16x8*)(cp + (size_t)(((ks2*4 + vt)*4 + g)*16 + col) * 8);
    #pragma unroll
    for(int mt=0; mt<4; ++mt)
      #pragma unroll
      for(int vt=0; vt<4; ++vt)
        y[mt][vt] = __builtin_amdgcn_mfma_f32_16x16x32_bf16(pa[mt], cv[vt], y[mt][vt], 0, 0, 0);
  }

  float* const ob = out + (size_t)b * 2097152;
  #pragma unroll
  for(int mt=0; mt<4; ++mt)
    #pragma unroll
    for(int vt=0; vt<4; ++vt){
      const size_t a = (size_t)(head*64 + vt*16 + col)*4096
                     + (size_t)(t0 + mt*16 + g*4);
      const float4 xr4 = *(const float4*)(xb + a);
      float4 o4;
      o4.x = xr4.x + y[mt][vt][0];
      o4.y = xr4.y + y[mt][vt][1];
      o4.z = xr4.z + y[mt][vt][2];
      o4.w = xr4.w + y[mt][vt][3];
      *(float4*)(ob + a) = o4;
    }
}

// ---------------------------------------------------------------------------
extern "C" void kernel_launch(void* const* d_in, const int* in_sizes, int n_in,
                              void* d_out, int out_size, void* d_ws, size_t ws_size,
                              hipStream_t stream)
{
  const float* input = (const float*)d_in[0];
  const float* cond  = (const float*)d_in[1];
  const int*   idx   = (const int*)d_in[2];
  const float* ln_g  = (const float*)d_in[3];
  const float* ln_b  = (const float*)d_in[4];
  const float* tln_g = (const float*)d_in[5];
  const float* tln_b = (const float*)d_in[6];
  const float* Wq    = (const float*)d_in[7];
  const float* bq    = (const float*)d_in[8];
  const float* Wk    = (const float*)d_in[9];
  const float* bk    = (const float*)d_in[10];
  const float* Wv    = (const float*)d_in[11];
  const float* bv    = (const float*)d_in[12];
  float* out = (float*)d_out;
  char*  ws  = (char*)d_ws;

  unsigned short* gWqT = (unsigned short*)(ws);                  // 512 KB
  float2*         c12  = (float2*)(ws + 524288);                 // 4 KB
  unsigned short* ctxP = (unsigned short*)(ws + 528384);         // 1.5 MB
  float* kbuf = (float*)(ws + 2101248);                          // 3.61 MB
  float* vbuf = (float*)(ws + 2101248 + 3784704);                // 3.61 MB

  k_aux  <<<dim3(4,5,25),  dim3(256), 0, stream>>>(Wq, ln_g, ln_b, bq, gWqT, c12,
                                                   cond, idx, tln_g, tln_b,
                                                   Wk, bk, Wv, bv, kbuf, vbuf);
  k_ctx  <<<dim3(8,24),    dim3(256), 0, stream>>>(kbuf, vbuf, ctxP);
  k_fused<<<dim3(2,1792),  dim3(256), 0, stream>>>(input, idx, gWqT, c12, ctxP, out);
}